// Round 1
// baseline (105.131 us; speedup 1.0000x reference)
//
#include <hip/hip_runtime.h>
#include <math.h>

#define NN  62
#define BGR 512
#define FIN 128
#define HD  64
#define NC  3

typedef __attribute__((ext_vector_type(8))) short          bf16x8;
typedef __attribute__((ext_vector_type(4))) float          f32x4;
typedef __attribute__((ext_vector_type(4))) unsigned short us4;

static __device__ __forceinline__ unsigned short f2bf(float f) {
    union { float f; unsigned u; } v; v.f = f;
    unsigned u = v.u;
    return (unsigned short)((u + 0x7fffu + ((u >> 16) & 1u)) >> 16);   // RNE
}
static __device__ __forceinline__ float bf2f(unsigned short h) {
    union { unsigned u; float f; } v; v.u = ((unsigned)h) << 16;
    return v.f;
}

// ---------------------------------------------------------------------------
// Workspace layout (ushort units):
//   A2HI [    0,  4096)   64x64
//   A2LO [ 4096,  8192)   64x64
//   WHI  [ 8192, 16896)   64x136 (stride-136 padded, matches LDS layout)
//   WLO  [16896, 25600)   64x136
// Total 25600 ushorts = 51200 B.
// ---------------------------------------------------------------------------

// Kernel A (1 block): graph-invariant precompute. Numerically identical to the
// previous fused kernel's dinv / A-build / A^2 path (same split-bf16 rounding,
// same MFMA order), so gcn_all's output is bit-identical to the verified code.
__global__ __launch_bounds__(256) void precomp(
    const float* __restrict__ tril, const float* __restrict__ W1,
    unsigned short* __restrict__ ws) {
    __shared__ unsigned short AH[9216];   // AHI 0..4608, ALO 4608..9216 (stride 72)
    __shared__ float dinvS[64];

    const int t = threadIdx.x;
    const int lane = t & 63, wv = t >> 6, quad = lane >> 4, l15 = lane & 15;

    // ---- W1 split-bf16 direct to ws (no dependencies) ----
    {
        const float4* w14 = (const float4*)W1;
        for (int e = t; e < 2048; e += 256) {
            int h = e >> 5, f4 = e & 31;
            float4 v = w14[e];
            us4 hh, ll;
            hh[0] = f2bf(v.x); ll[0] = f2bf(v.x - bf2f(hh[0]));
            hh[1] = f2bf(v.y); ll[1] = f2bf(v.y - bf2f(hh[1]));
            hh[2] = f2bf(v.z); ll[2] = f2bf(v.z - bf2f(hh[2]));
            hh[3] = f2bf(v.w); ll[3] = f2bf(v.w - bf2f(hh[3]));
            *(us4*)&ws[ 8192 + h * 136 + f4 * 4] = hh;
            *(us4*)&ws[16896 + h * 136 + f4 * 4] = ll;
        }
    }

    // ---- dinv ----
    if (t < 64) {
        float s = 0.f;
        if (t < NN) {
            for (int j = 0; j < NN; ++j) {
                int hi = max(t, j), lo = min(t, j);
                s += fabsf(tril[hi * (hi + 1) / 2 + lo]);
            }
            s = (s > 0.f) ? (1.0f / sqrtf(s)) : 0.f;
        }
        dinvS[t] = s;     // 0 for rows 62,63
    }
    __syncthreads();

    // ---- A = D^-1/2 W D^-1/2 as split-bf16 (rows/cols >=62 zero) ----
    for (int e4 = t; e4 < 1024; e4 += 256) {
        int i = e4 >> 4, j0 = (e4 & 15) * 4;
        float di = dinvS[i];
        float4 dj4 = *(float4*)&dinvS[j0];
        float dja[4] = {dj4.x, dj4.y, dj4.z, dj4.w};
        us4 hh, ll;
#pragma unroll
        for (int r = 0; r < 4; ++r) {
            int j = j0 + r;
            float w = 0.f;
            if (i < NN && j < NN) {
                int hi = max(i, j), lo = min(i, j);
                w = tril[hi * (hi + 1) / 2 + lo];
            }
            float v = di * w * dja[r];
            hh[r] = f2bf(v);
            ll[r] = f2bf(v - bf2f(hh[r]));
        }
        *(us4*)&AH[       i * 72 + j0] = hh;
        *(us4*)&AH[4608 + i * 72 + j0] = ll;
    }
    __syncthreads();

    // ---- A^2 = A @ A via MFMA (A symmetric: row-major serves A- and B-frags) ----
    f32x4 za0 = {0,0,0,0}, za1 = {0,0,0,0}, za2 = {0,0,0,0}, za3 = {0,0,0,0};
    {
        const int arow = (16 * wv + l15) * 72 + quad * 8;
#pragma unroll
        for (int c = 0; c < 2; ++c) {
            bf16x8 ahi = *(bf16x8*)&AH[arow + c * 32];
            bf16x8 alo = *(bf16x8*)&AH[4608 + arow + c * 32];
#define ATILE(ACC, NT) { \
            int bo = (16 * NT + l15) * 72 + quad * 8 + c * 32; \
            bf16x8 bhi = *(bf16x8*)&AH[bo]; \
            bf16x8 blo = *(bf16x8*)&AH[4608 + bo]; \
            ACC = __builtin_amdgcn_mfma_f32_16x16x32_bf16(ahi, bhi, ACC, 0, 0, 0); \
            ACC = __builtin_amdgcn_mfma_f32_16x16x32_bf16(ahi, blo, ACC, 0, 0, 0); \
            ACC = __builtin_amdgcn_mfma_f32_16x16x32_bf16(alo, bhi, ACC, 0, 0, 0); \
            ACC = __builtin_amdgcn_mfma_f32_16x16x32_bf16(alo, blo, ACC, 0, 0, 0); }
            ATILE(za0, 0) ATILE(za1, 1) ATILE(za2, 2) ATILE(za3, 3)
#undef ATILE
        }
    }

    // ---- store A^2 split to ws (A^2 symmetric: transposed C-store == itself) ----
    {
        const int mbase = 16 * wv + quad * 4;
#define A2W(ACC, NT) { \
        int n = 16 * NT + l15; \
        us4 hh, ll; \
        hh[0] = f2bf(ACC[0]); ll[0] = f2bf(ACC[0] - bf2f(hh[0])); \
        hh[1] = f2bf(ACC[1]); ll[1] = f2bf(ACC[1] - bf2f(hh[1])); \
        hh[2] = f2bf(ACC[2]); ll[2] = f2bf(ACC[2] - bf2f(hh[2])); \
        hh[3] = f2bf(ACC[3]); ll[3] = f2bf(ACC[3] - bf2f(hh[3])); \
        *(us4*)&ws[       n * 64 + mbase] = hh; \
        *(us4*)&ws[4096 + n * 64 + mbase] = ll; }
        A2W(za0, 0) A2W(za1, 1) A2W(za2, 2) A2W(za3, 3)
#undef A2W
    }
}

// ---------------------------------------------------------------------------
// Kernel B (512 blocks): per-graph work only.
// LDS (ushort offsets):
//   phase 1: XHI 0..8704 (64x136), XLO 8704..17408
//            WHI 17408..26112, WLO 26112..34816 (verbatim copy from ws)
//   phase 2: YTHI 0..4608 (64x72), YTLO 4608..9216  (overwrites X after P1)
// A^2 MFMA fragments are read straight from ws (global, L2-hot broadcast)
// into registers at kernel entry — no LDS staging, latency hidden under
// the X staging phase. 69.6 KB + 4.6 KB TAIL -> 2 blocks/CU unchanged.
// ---------------------------------------------------------------------------
__global__ __launch_bounds__(256) void gcn_all(
    const float* __restrict__ x, const float* __restrict__ b1,
    const float* __restrict__ W2, const float* __restrict__ b2,
    const unsigned short* __restrict__ ws, float* __restrict__ out) {
    __shared__ unsigned short SH[34816];          // 68 KB
    __shared__ float TAIL[1088 + 64];             // partial(64x17), b1S(64)
    float* partial = TAIL;
    float* b1S     = TAIL + 1088;

    const int t = threadIdx.x;
    const int g = blockIdx.x;
    const int lane = t & 63, wv = t >> 6, quad = lane >> 4, l15 = lane & 15;

    if (t < 16) *(float4*)&b1S[4 * t] = ((const float4*)b1)[t];

    // ---- A^2 fragments from ws: issued first, consumed in P2 ----
    const int a2off = (16 * wv + l15) * 64 + quad * 8;
    bf16x8 A2h0 = *(const bf16x8*)&ws[a2off];
    bf16x8 A2l0 = *(const bf16x8*)&ws[4096 + a2off];
    bf16x8 A2h1 = *(const bf16x8*)&ws[a2off + 32];
    bf16x8 A2l1 = *(const bf16x8*)&ws[4096 + a2off + 32];

    // ---- stage X split; rows 62,63 zeroed ----
    const float4* xg4 = (const float4*)(x + (size_t)g * NN * FIN);
    for (int e = t; e < 2048; e += 256) {
        int row = e >> 5, k4 = e & 31;
        float4 v = {0.f, 0.f, 0.f, 0.f};
        if (e < 1984) v = xg4[e];
        us4 hh, ll;
        hh[0] = f2bf(v.x); ll[0] = f2bf(v.x - bf2f(hh[0]));
        hh[1] = f2bf(v.y); ll[1] = f2bf(v.y - bf2f(hh[1]));
        hh[2] = f2bf(v.z); ll[2] = f2bf(v.z - bf2f(hh[2]));
        hh[3] = f2bf(v.w); ll[3] = f2bf(v.w - bf2f(hh[3]));
        *(us4*)&SH[       row * 136 + k4 * 4] = hh;
        *(us4*)&SH[8704 + row * 136 + k4 * 4] = ll;
    }
    // ---- stage W1 split: verbatim vector copy from ws (no conversion math) ----
    {
        const uint4* src = (const uint4*)(ws + 8192);
        uint4* dst = (uint4*)(SH + 17408);
        for (int i = t; i < 2176; i += 256) dst[i] = src[i];   // 34816 B
    }
    __syncthreads();

    // ---- P1: Y = X @ W1^T ----
    f32x4 y0 = {0,0,0,0}, y1 = {0,0,0,0}, y2 = {0,0,0,0}, y3 = {0,0,0,0};
    {
        const int arow = (16 * wv + l15) * 136 + quad * 8;
#pragma unroll
        for (int c = 0; c < 4; ++c) {
            bf16x8 ahi = *(bf16x8*)&SH[arow + c * 32];
            bf16x8 alo = *(bf16x8*)&SH[8704 + arow + c * 32];
#define P1TILE(ACC, NT) { \
            int bo = (16 * NT + l15) * 136 + quad * 8 + c * 32; \
            bf16x8 bhi = *(bf16x8*)&SH[17408 + bo]; \
            bf16x8 blo = *(bf16x8*)&SH[26112 + bo]; \
            ACC = __builtin_amdgcn_mfma_f32_16x16x32_bf16(ahi, bhi, ACC, 0, 0, 0); \
            ACC = __builtin_amdgcn_mfma_f32_16x16x32_bf16(ahi, blo, ACC, 0, 0, 0); \
            ACC = __builtin_amdgcn_mfma_f32_16x16x32_bf16(alo, bhi, ACC, 0, 0, 0); \
            ACC = __builtin_amdgcn_mfma_f32_16x16x32_bf16(alo, blo, ACC, 0, 0, 0); }
            P1TILE(y0, 0) P1TILE(y1, 1) P1TILE(y2, 2) P1TILE(y3, 3)
#undef P1TILE
        }
    }
    __syncthreads();   // all P1 LDS reads done -> X region reusable

    // ---- write YT (transposed) into former X region ----
    {
        const int mbase = 16 * wv + quad * 4;
#define SPLITW(ACC, NT) { \
        int n = 16 * NT + l15; \
        us4 hh, ll; \
        hh[0] = f2bf(ACC[0]); ll[0] = f2bf(ACC[0] - bf2f(hh[0])); \
        hh[1] = f2bf(ACC[1]); ll[1] = f2bf(ACC[1] - bf2f(hh[1])); \
        hh[2] = f2bf(ACC[2]); ll[2] = f2bf(ACC[2] - bf2f(hh[2])); \
        hh[3] = f2bf(ACC[3]); ll[3] = f2bf(ACC[3] - bf2f(hh[3])); \
        *(us4*)&SH[       n * 72 + mbase] = hh; \
        *(us4*)&SH[4608 + n * 72 + mbase] = ll; }
        SPLITW(y0, 0) SPLITW(y1, 1) SPLITW(y2, 2) SPLITW(y3, 3)
#undef SPLITW
    }
    __syncthreads();

    // ---- P2: Z = A2 @ Y (A-frags already in registers) ----
    f32x4 z0 = {0,0,0,0}, z1 = {0,0,0,0}, z2 = {0,0,0,0}, z3 = {0,0,0,0};
    {
#define P2TILE(ACC, NT, AH_, AL_, CO) { \
        int bo = (16 * NT + l15) * 72 + quad * 8 + CO; \
        bf16x8 bhi = *(bf16x8*)&SH[bo]; \
        bf16x8 blo = *(bf16x8*)&SH[4608 + bo]; \
        ACC = __builtin_amdgcn_mfma_f32_16x16x32_bf16(AH_, bhi, ACC, 0, 0, 0); \
        ACC = __builtin_amdgcn_mfma_f32_16x16x32_bf16(AH_, blo, ACC, 0, 0, 0); \
        ACC = __builtin_amdgcn_mfma_f32_16x16x32_bf16(AL_, bhi, ACC, 0, 0, 0); \
        ACC = __builtin_amdgcn_mfma_f32_16x16x32_bf16(AL_, blo, ACC, 0, 0, 0); }
        P2TILE(z0, 0, A2h0, A2l0, 0) P2TILE(z1, 1, A2h0, A2l0, 0)
        P2TILE(z2, 2, A2h0, A2l0, 0) P2TILE(z3, 3, A2h0, A2l0, 0)
        P2TILE(z0, 0, A2h1, A2l1, 32) P2TILE(z1, 1, A2h1, A2l1, 32)
        P2TILE(z2, 2, A2h1, A2l1, 32) P2TILE(z3, 3, A2h1, A2l1, 32)
#undef P2TILE
    }

    // ---- epilogue: +b1, relu, mask pad rows, partial pool ----
    {
        const int mbase = 16 * wv + quad * 4;
        const int slot = 4 * wv + quad;
#define POOL(ACC, NT) { \
        int n = 16 * NT + l15; \
        float bn = b1S[n]; \
        float p = 0.f; \
        if (mbase + 0 < 62) p += fmaxf(ACC[0] + bn, 0.f); \
        if (mbase + 1 < 62) p += fmaxf(ACC[1] + bn, 0.f); \
        if (mbase + 2 < 62) p += fmaxf(ACC[2] + bn, 0.f); \
        if (mbase + 3 < 62) p += fmaxf(ACC[3] + bn, 0.f); \
        partial[n * 17 + slot] = p; }
        POOL(z0, 0) POOL(z1, 1) POOL(z2, 2) POOL(z3, 3)
#undef POOL
    }
    __syncthreads();

    // ---- wave-0 tail: pool-reduce, latent write, logits via shuffle, log_softmax ----
    if (t < HD) {
        float s = 0.f;
#pragma unroll
        for (int q = 0; q < 16; ++q) s += partial[t * 17 + q];
        out[(size_t)g * HD + t] = s;
        float l0 = s * W2[t];                 // W2 rows: [c][h], 768 B, L2-hot
        float l1 = s * W2[64 + t];
        float l2 = s * W2[128 + t];
#pragma unroll
        for (int off = 32; off > 0; off >>= 1) {
            l0 += __shfl_down(l0, off);
            l1 += __shfl_down(l1, off);
            l2 += __shfl_down(l2, off);
        }
        if (t == 0) {
            l0 += b2[0]; l1 += b2[1]; l2 += b2[2];
            float m = fmaxf(l0, fmaxf(l1, l2));
            float lse = m + logf(expf(l0 - m) + expf(l1 - m) + expf(l2 - m));
            float* lp = out + (size_t)BGR * HD + (size_t)g * NC;
            lp[0] = l0 - lse; lp[1] = l1 - lse; lp[2] = l2 - lse;
        }
    }
}

extern "C" void kernel_launch(void* const* d_in, const int* in_sizes, int n_in,
                              void* d_out, int out_size, void* d_ws, size_t ws_size,
                              hipStream_t stream) {
    const float* x    = (const float*)d_in[0];
    const float* tril = (const float*)d_in[1];
    const float* W1   = (const float*)d_in[2];
    const float* b1   = (const float*)d_in[3];
    const float* W2   = (const float*)d_in[4];
    const float* b2   = (const float*)d_in[5];
    float* out = (float*)d_out;
    unsigned short* ws = (unsigned short*)d_ws;   // needs 51200 B

    precomp<<<1, 256, 0, stream>>>(tril, W1, ws);
    gcn_all<<<BGR, 256, 0, stream>>>(x, b1, W2, b2, ws, out);
}

// Round 2
// 100.655 us; speedup vs baseline: 1.0445x; 1.0445x over previous
//
#include <hip/hip_runtime.h>
#include <math.h>

#define NN  62
#define BGR 512
#define FIN 128
#define HD  64
#define NC  3

typedef __attribute__((ext_vector_type(8))) short          bf16x8;
typedef __attribute__((ext_vector_type(4))) float          f32x4;
typedef __attribute__((ext_vector_type(4))) unsigned short us4;

static __device__ __forceinline__ unsigned short f2bf(float f) {
    union { float f; unsigned u; } v; v.f = f;
    unsigned u = v.u;
    return (unsigned short)((u + 0x7fffu + ((u >> 16) & 1u)) >> 16);   // RNE
}
static __device__ __forceinline__ float bf2f(unsigned short h) {
    union { unsigned u; float f; } v; v.u = ((unsigned)h) << 16;
    return v.f;
}

// Single fused kernel, v3.
// Key structural changes vs the 102.3 µs version:
//  - X is never staged in LDS: each lane loads its P1 A-fragment directly from
//    global (32 B contiguous per lane per k-chunk; 128-B segments per wave) and
//    converts to split-bf16 in registers. Deletes the 2048-iter staging loop,
//    34 KB LDS, and 2 barriers.
//  - lo*lo MFMA term dropped everywhere (contributes ~2^-16 relative; 25% of
//    all MFMAs).
//  - 5 barriers total on the main path (was 7).
// LDS map (ushort offsets in SH):
//  WHI [0,8704) stride 136 | WLO [8704,17408)
//  AHI [17408,22016) stride 72 | ALO [22016,26624)   (overwritten by A2HI/LO)
//  YTHI [26624,31232) stride 72 | YTLO [31232,35840)
__global__ __launch_bounds__(256) void gcn_all(
    const float* __restrict__ x, const float* __restrict__ tril,
    const float* __restrict__ W1, const float* __restrict__ b1,
    const float* __restrict__ W2, const float* __restrict__ b2,
    float* __restrict__ out) {
    __shared__ unsigned short SH[35840];          // 70 KB
    __shared__ float TAIL[1088 + 64 + 64];        // partial(64x17), b1S(64), dinv(64)
    float* partial = TAIL;
    float* b1S     = TAIL + 1088;
    float* dinvS   = TAIL + 1152;

    const int t = threadIdx.x;
    const int g = blockIdx.x;
    const int lane = t & 63, wv = t >> 6, quad = lane >> 4, l15 = lane & 15;

    if (t < 16) *(float4*)&b1S[4 * t] = ((const float4*)b1)[t];

    // ---- X fragments: direct global -> regs (no LDS). Rows 62,63 zeroed. ----
    bf16x8 xh[4], xl[4];
    {
        const int xr = 16 * wv + l15;
        if (xr < NN) {
            const float* xrow = x + (size_t)g * NN * FIN + (size_t)xr * FIN + quad * 8;
#pragma unroll
            for (int c = 0; c < 4; ++c) {
                float4 a = *(const float4*)(xrow + c * 32);
                float4 b = *(const float4*)(xrow + c * 32 + 4);
                float vv[8] = {a.x, a.y, a.z, a.w, b.x, b.y, b.z, b.w};
#pragma unroll
                for (int k = 0; k < 8; ++k) {
                    unsigned short h = f2bf(vv[k]);
                    xh[c][k] = (short)h;
                    xl[c][k] = (short)f2bf(vv[k] - bf2f(h));
                }
            }
        } else {
            bf16x8 zv = {0, 0, 0, 0, 0, 0, 0, 0};
#pragma unroll
            for (int c = 0; c < 4; ++c) { xh[c] = zv; xl[c] = zv; }
        }
    }

    // ---- dinv (t<64; tril is 7.8 KB, L2-hot after first blocks) ----
    if (t < 64) {
        float s = 0.f;
        if (t < NN) {
            for (int j = 0; j < NN; ++j) {
                int hi = max(t, j), lo = min(t, j);
                s += fabsf(tril[hi * (hi + 1) / 2 + lo]);
            }
            s = (s > 0.f) ? (1.0f / sqrtf(s)) : 0.f;
        }
        dinvS[t] = s;     // 0 for rows 62,63
    }
    __syncthreads();      // (1) dinv ready

    // ---- A = D^-1/2 W D^-1/2 split-bf16 (rows/cols >=62 zero) ----
    for (int e4 = t; e4 < 1024; e4 += 256) {
        int i = e4 >> 4, j0 = (e4 & 15) * 4;
        float di = dinvS[i];
        float4 dj4 = *(float4*)&dinvS[j0];
        float dja[4] = {dj4.x, dj4.y, dj4.z, dj4.w};
        us4 hh, ll;
#pragma unroll
        for (int r = 0; r < 4; ++r) {
            int j = j0 + r;
            float w = 0.f;
            if (i < NN && j < NN) {
                int hi = max(i, j), lo = min(i, j);
                w = tril[hi * (hi + 1) / 2 + lo];
            }
            float v = di * w * dja[r];
            hh[r] = f2bf(v);
            ll[r] = f2bf(v - bf2f(hh[r]));
        }
        *(us4*)&SH[17408 + i * 72 + j0] = hh;
        *(us4*)&SH[22016 + i * 72 + j0] = ll;
    }
    // ---- stage W1 split (independent of dinv/A; same barrier covers both) ----
    {
        const float4* w14 = (const float4*)W1;
        for (int e = t; e < 2048; e += 256) {
            int h = e >> 5, f4 = e & 31;
            float4 v = w14[e];
            us4 hh, ll;
            hh[0] = f2bf(v.x); ll[0] = f2bf(v.x - bf2f(hh[0]));
            hh[1] = f2bf(v.y); ll[1] = f2bf(v.y - bf2f(hh[1]));
            hh[2] = f2bf(v.z); ll[2] = f2bf(v.z - bf2f(hh[2]));
            hh[3] = f2bf(v.w); ll[3] = f2bf(v.w - bf2f(hh[3]));
            *(us4*)&SH[       h * 136 + f4 * 4] = hh;
            *(us4*)&SH[8704 + h * 136 + f4 * 4] = ll;
        }
    }
    __syncthreads();      // (2) A + W staged

    // ---- A^2 = A @ A via MFMA, 3-term split (lo*lo dropped), result in regs ----
    f32x4 za0 = {0,0,0,0}, za1 = {0,0,0,0}, za2 = {0,0,0,0}, za3 = {0,0,0,0};
    {
        const int arow = 17408 + (16 * wv + l15) * 72 + quad * 8;
#pragma unroll
        for (int c = 0; c < 2; ++c) {
            bf16x8 ahi = *(bf16x8*)&SH[arow + c * 32];
            bf16x8 alo = *(bf16x8*)&SH[4608 + arow + c * 32];
#define ATILE(ACC, NT) { \
            int bo = 17408 + (16 * NT + l15) * 72 + quad * 8 + c * 32; \
            bf16x8 bhi = *(bf16x8*)&SH[bo]; \
            bf16x8 blo = *(bf16x8*)&SH[4608 + bo]; \
            ACC = __builtin_amdgcn_mfma_f32_16x16x32_bf16(ahi, bhi, ACC, 0, 0, 0); \
            ACC = __builtin_amdgcn_mfma_f32_16x16x32_bf16(ahi, blo, ACC, 0, 0, 0); \
            ACC = __builtin_amdgcn_mfma_f32_16x16x32_bf16(alo, bhi, ACC, 0, 0, 0); }
            ATILE(za0, 0) ATILE(za1, 1) ATILE(za2, 2) ATILE(za3, 3)
#undef ATILE
        }
    }

    // ---- P1: Y = X @ W1^T (A-frags from regs), 3-term split ----
    f32x4 y0 = {0,0,0,0}, y1 = {0,0,0,0}, y2 = {0,0,0,0}, y3 = {0,0,0,0};
    {
#pragma unroll
        for (int c = 0; c < 4; ++c) {
            bf16x8 ahi = xh[c];
            bf16x8 alo = xl[c];
#define P1TILE(ACC, NT) { \
            int bo = (16 * NT + l15) * 136 + quad * 8 + c * 32; \
            bf16x8 bhi = *(bf16x8*)&SH[bo]; \
            bf16x8 blo = *(bf16x8*)&SH[8704 + bo]; \
            ACC = __builtin_amdgcn_mfma_f32_16x16x32_bf16(ahi, bhi, ACC, 0, 0, 0); \
            ACC = __builtin_amdgcn_mfma_f32_16x16x32_bf16(ahi, blo, ACC, 0, 0, 0); \
            ACC = __builtin_amdgcn_mfma_f32_16x16x32_bf16(alo, bhi, ACC, 0, 0, 0); }
            P1TILE(y0, 0) P1TILE(y1, 1) P1TILE(y2, 2) P1TILE(y3, 3)
#undef P1TILE
        }
    }
    __syncthreads();      // (3) all A-region reads done -> may overwrite with A2

    // ---- write YT (transposed) and A2 (symmetric -> transposed store == itself) ----
    {
        const int mbase = 16 * wv + quad * 4;
#define SPLITW(ACC, NT, HIOFF, LOOFF) { \
        int n = 16 * NT + l15; \
        us4 hh, ll; \
        hh[0] = f2bf(ACC[0]); ll[0] = f2bf(ACC[0] - bf2f(hh[0])); \
        hh[1] = f2bf(ACC[1]); ll[1] = f2bf(ACC[1] - bf2f(hh[1])); \
        hh[2] = f2bf(ACC[2]); ll[2] = f2bf(ACC[2] - bf2f(hh[2])); \
        hh[3] = f2bf(ACC[3]); ll[3] = f2bf(ACC[3] - bf2f(hh[3])); \
        *(us4*)&SH[(HIOFF) + n * 72 + mbase] = hh; \
        *(us4*)&SH[(LOOFF) + n * 72 + mbase] = ll; }
        SPLITW(y0, 0, 26624, 31232) SPLITW(y1, 1, 26624, 31232)
        SPLITW(y2, 2, 26624, 31232) SPLITW(y3, 3, 26624, 31232)
        SPLITW(za0, 0, 17408, 22016) SPLITW(za1, 1, 17408, 22016)
        SPLITW(za2, 2, 17408, 22016) SPLITW(za3, 3, 17408, 22016)
#undef SPLITW
    }
    __syncthreads();      // (4) A2 + YT staged

    // ---- P2: Z = A2 @ Y, 3-term split ----
    f32x4 z0 = {0,0,0,0}, z1 = {0,0,0,0}, z2 = {0,0,0,0}, z3 = {0,0,0,0};
    {
        const int arow = 17408 + (16 * wv + l15) * 72 + quad * 8;
#pragma unroll
        for (int c = 0; c < 2; ++c) {
            bf16x8 ahi = *(bf16x8*)&SH[arow + c * 32];
            bf16x8 alo = *(bf16x8*)&SH[4608 + arow + c * 32];
#define P2TILE(ACC, NT) { \
            int bo = 26624 + (16 * NT + l15) * 72 + quad * 8 + c * 32; \
            bf16x8 bhi = *(bf16x8*)&SH[bo]; \
            bf16x8 blo = *(bf16x8*)&SH[4608 + bo]; \
            ACC = __builtin_amdgcn_mfma_f32_16x16x32_bf16(ahi, bhi, ACC, 0, 0, 0); \
            ACC = __builtin_amdgcn_mfma_f32_16x16x32_bf16(ahi, blo, ACC, 0, 0, 0); \
            ACC = __builtin_amdgcn_mfma_f32_16x16x32_bf16(alo, bhi, ACC, 0, 0, 0); }
            P2TILE(z0, 0) P2TILE(z1, 1) P2TILE(z2, 2) P2TILE(z3, 3)
#undef P2TILE
        }
    }

    // ---- epilogue: +b1, relu, mask pad rows, partial pool ----
    {
        const int mbase = 16 * wv + quad * 4;
        const int slot = 4 * wv + quad;
#define POOL(ACC, NT) { \
        int n = 16 * NT + l15; \
        float bn = b1S[n]; \
        float p = 0.f; \
        if (mbase + 0 < 62) p += fmaxf(ACC[0] + bn, 0.f); \
        if (mbase + 1 < 62) p += fmaxf(ACC[1] + bn, 0.f); \
        if (mbase + 2 < 62) p += fmaxf(ACC[2] + bn, 0.f); \
        if (mbase + 3 < 62) p += fmaxf(ACC[3] + bn, 0.f); \
        partial[n * 17 + slot] = p; }
        POOL(z0, 0) POOL(z1, 1) POOL(z2, 2) POOL(z3, 3)
#undef POOL
    }
    __syncthreads();      // (5) partials ready

    // ---- wave-0 tail: pool-reduce, latent write, logits via shuffle, log_softmax ----
    if (t < HD) {
        float s = 0.f;
#pragma unroll
        for (int q = 0; q < 16; ++q) s += partial[t * 17 + q];
        out[(size_t)g * HD + t] = s;
        float l0 = s * W2[t];                 // W2 rows: [c][h], 768 B, L2-hot
        float l1 = s * W2[64 + t];
        float l2 = s * W2[128 + t];
#pragma unroll
        for (int off = 32; off > 0; off >>= 1) {
            l0 += __shfl_down(l0, off);
            l1 += __shfl_down(l1, off);
            l2 += __shfl_down(l2, off);
        }
        if (t == 0) {
            l0 += b2[0]; l1 += b2[1]; l2 += b2[2];
            float m = fmaxf(l0, fmaxf(l1, l2));
            float lse = m + logf(expf(l0 - m) + expf(l1 - m) + expf(l2 - m));
            float* lp = out + (size_t)BGR * HD + (size_t)g * NC;
            lp[0] = l0 - lse; lp[1] = l1 - lse; lp[2] = l2 - lse;
        }
    }
}

extern "C" void kernel_launch(void* const* d_in, const int* in_sizes, int n_in,
                              void* d_out, int out_size, void* d_ws, size_t ws_size,
                              hipStream_t stream) {
    const float* x    = (const float*)d_in[0];
    const float* tril = (const float*)d_in[1];
    const float* W1   = (const float*)d_in[2];
    const float* b1   = (const float*)d_in[3];
    const float* W2   = (const float*)d_in[4];
    const float* b2   = (const float*)d_in[5];
    float* out = (float*)d_out;

    gcn_all<<<BGR, 256, 0, stream>>>(x, tril, W1, b1, W2, b2, out);
}

// Round 3
// 95.245 us; speedup vs baseline: 1.1038x; 1.0568x over previous
//
#include <hip/hip_runtime.h>
#include <math.h>

#define NN  62
#define BGR 512
#define FIN 128
#define HD  64
#define NC  3

typedef __attribute__((ext_vector_type(8))) short          bf16x8;
typedef __attribute__((ext_vector_type(4))) float          f32x4;
typedef __attribute__((ext_vector_type(4))) unsigned short us4;

static __device__ __forceinline__ unsigned short f2bf(float f) {
    union { float f; unsigned u; } v; v.f = f;
    unsigned u = v.u;
    return (unsigned short)((u + 0x7fffu + ((u >> 16) & 1u)) >> 16);   // RNE
}
static __device__ __forceinline__ float bf2f(unsigned short h) {
    union { unsigned u; float f; } v; v.u = ((unsigned)h) << 16;
    return v.f;
}

// Single fused kernel, v4.
// vs v3 (100.7 µs):
//  - dinv is computed by ALL 256 threads (thread = (row 16wv+l15, col-chunk
//    16*quad)): 16 tril gathers/thread + 2 __shfl_xor row-reduce. No more
//    wave-0-only 62-load serial phase while 3 waves idle at the barrier.
//  - The 16 tril elements loaded for dinv are kept in registers and reused
//    for the A-build tile (same (row, col-chunk) assignment) -> A-build does
//    ZERO tril reloads; own-row dinv comes straight from a register.
//  - Everything else (X direct-to-reg fragments, 3-term split MFMA, 5
//    barriers, LDS map) identical to v3.
// LDS map (ushort offsets in SH):
//  WHI [0,8704) stride 136 | WLO [8704,17408)
//  AHI [17408,22016) stride 72 | ALO [22016,26624)   (overwritten by A2HI/LO)
//  YTHI [26624,31232) stride 72 | YTLO [31232,35840)
__global__ __launch_bounds__(256) void gcn_all(
    const float* __restrict__ x, const float* __restrict__ tril,
    const float* __restrict__ W1, const float* __restrict__ b1,
    const float* __restrict__ W2, const float* __restrict__ b2,
    float* __restrict__ out) {
    __shared__ unsigned short SH[35840];          // 70 KB
    __shared__ float TAIL[1088 + 64 + 64];        // partial(64x17), b1S(64), dinv(64)
    float* partial = TAIL;
    float* b1S     = TAIL + 1088;
    float* dinvS   = TAIL + 1152;

    const int t = threadIdx.x;
    const int g = blockIdx.x;
    const int lane = t & 63, wv = t >> 6, quad = lane >> 4, l15 = lane & 15;

    if (t < 16) *(float4*)&b1S[4 * t] = ((const float4*)b1)[t];

    // ---- stage W1 split (no dependencies; issue its global loads first) ----
    {
        const float4* w14 = (const float4*)W1;
        for (int e = t; e < 2048; e += 256) {
            int h = e >> 5, f4 = e & 31;
            float4 v = w14[e];
            us4 hh, ll;
            hh[0] = f2bf(v.x); ll[0] = f2bf(v.x - bf2f(hh[0]));
            hh[1] = f2bf(v.y); ll[1] = f2bf(v.y - bf2f(hh[1]));
            hh[2] = f2bf(v.z); ll[2] = f2bf(v.z - bf2f(hh[2]));
            hh[3] = f2bf(v.w); ll[3] = f2bf(v.w - bf2f(hh[3]));
            *(us4*)&SH[       h * 136 + f4 * 4] = hh;
            *(us4*)&SH[8704 + h * 136 + f4 * 4] = ll;
        }
    }

    // ---- X fragments: direct global -> regs (no LDS). Rows 62,63 zeroed. ----
    bf16x8 xh[4], xl[4];
    {
        const int xr = 16 * wv + l15;
        if (xr < NN) {
            const float* xrow = x + (size_t)g * NN * FIN + (size_t)xr * FIN + quad * 8;
#pragma unroll
            for (int c = 0; c < 4; ++c) {
                float4 a = *(const float4*)(xrow + c * 32);
                float4 b = *(const float4*)(xrow + c * 32 + 4);
                float vv[8] = {a.x, a.y, a.z, a.w, b.x, b.y, b.z, b.w};
#pragma unroll
                for (int k = 0; k < 8; ++k) {
                    unsigned short h = f2bf(vv[k]);
                    xh[c][k] = (short)h;
                    xl[c][k] = (short)f2bf(vv[k] - bf2f(h));
                }
            }
        } else {
            bf16x8 zv = {0, 0, 0, 0, 0, 0, 0, 0};
#pragma unroll
            for (int c = 0; c < 4; ++c) { xh[c] = zv; xl[c] = zv; }
        }
    }

    // ---- dinv, all-thread parallel; keep W_sym tile in regs for A-build ----
    const int arow_i = 16 * wv + l15;      // this thread's A row
    const int jbase  = 16 * quad;          // this thread's A col-chunk
    float wreg[16];
    float dinv_r;                          // dinv of own row (register)
    {
        float ps = 0.f;
#pragma unroll
        for (int jj = 0; jj < 16; ++jj) {
            int j = jbase + jj;
            float w = 0.f;
            if (arow_i < NN && j < NN) {
                int hi = arow_i > j ? arow_i : j;
                int lo = arow_i > j ? j : arow_i;
                w = tril[hi * (hi + 1) / 2 + lo];
            }
            wreg[jj] = w;
            ps += fabsf(w);
        }
        ps += __shfl_xor(ps, 16);          // quads 0<->1, 2<->3
        ps += __shfl_xor(ps, 32);          // quads {0,2}<->{1,3}
        dinv_r = (ps > 0.f) ? (1.0f / sqrtf(ps)) : 0.f;   // 0 for rows >=62
        if (lane < 16) dinvS[16 * wv + lane] = dinv_r;
    }
    __syncthreads();      // (1) dinvS ready

    // ---- A = D^-1/2 W D^-1/2 split-bf16 from registers (no tril reload) ----
    {
        const float di = dinv_r;
#pragma unroll
        for (int k = 0; k < 4; ++k) {
            float4 d4 = *(float4*)&dinvS[jbase + 4 * k];
            float dja[4] = {d4.x, d4.y, d4.z, d4.w};
            us4 hh, ll;
#pragma unroll
            for (int e = 0; e < 4; ++e) {
                float v = di * wreg[4 * k + e] * dja[e];
                hh[e] = f2bf(v);
                ll[e] = f2bf(v - bf2f(hh[e]));
            }
            *(us4*)&SH[17408 + arow_i * 72 + jbase + 4 * k] = hh;
            *(us4*)&SH[22016 + arow_i * 72 + jbase + 4 * k] = ll;
        }
    }
    __syncthreads();      // (2) A staged (W staged before barrier 1)

    // ---- A^2 = A @ A via MFMA, 3-term split (lo*lo dropped), result in regs ----
    f32x4 za0 = {0,0,0,0}, za1 = {0,0,0,0}, za2 = {0,0,0,0}, za3 = {0,0,0,0};
    {
        const int arow = 17408 + (16 * wv + l15) * 72 + quad * 8;
#pragma unroll
        for (int c = 0; c < 2; ++c) {
            bf16x8 ahi = *(bf16x8*)&SH[arow + c * 32];
            bf16x8 alo = *(bf16x8*)&SH[4608 + arow + c * 32];
#define ATILE(ACC, NT) { \
            int bo = 17408 + (16 * NT + l15) * 72 + quad * 8 + c * 32; \
            bf16x8 bhi = *(bf16x8*)&SH[bo]; \
            bf16x8 blo = *(bf16x8*)&SH[4608 + bo]; \
            ACC = __builtin_amdgcn_mfma_f32_16x16x32_bf16(ahi, bhi, ACC, 0, 0, 0); \
            ACC = __builtin_amdgcn_mfma_f32_16x16x32_bf16(ahi, blo, ACC, 0, 0, 0); \
            ACC = __builtin_amdgcn_mfma_f32_16x16x32_bf16(alo, bhi, ACC, 0, 0, 0); }
            ATILE(za0, 0) ATILE(za1, 1) ATILE(za2, 2) ATILE(za3, 3)
#undef ATILE
        }
    }

    // ---- P1: Y = X @ W1^T (A-frags from regs), 3-term split ----
    f32x4 y0 = {0,0,0,0}, y1 = {0,0,0,0}, y2 = {0,0,0,0}, y3 = {0,0,0,0};
    {
#pragma unroll
        for (int c = 0; c < 4; ++c) {
            bf16x8 ahi = xh[c];
            bf16x8 alo = xl[c];
#define P1TILE(ACC, NT) { \
            int bo = (16 * NT + l15) * 136 + quad * 8 + c * 32; \
            bf16x8 bhi = *(bf16x8*)&SH[bo]; \
            bf16x8 blo = *(bf16x8*)&SH[8704 + bo]; \
            ACC = __builtin_amdgcn_mfma_f32_16x16x32_bf16(ahi, bhi, ACC, 0, 0, 0); \
            ACC = __builtin_amdgcn_mfma_f32_16x16x32_bf16(ahi, blo, ACC, 0, 0, 0); \
            ACC = __builtin_amdgcn_mfma_f32_16x16x32_bf16(alo, bhi, ACC, 0, 0, 0); }
            P1TILE(y0, 0) P1TILE(y1, 1) P1TILE(y2, 2) P1TILE(y3, 3)
#undef P1TILE
        }
    }
    __syncthreads();      // (3) all A-region reads done -> may overwrite with A2

    // ---- write YT (transposed) and A2 (symmetric -> transposed store == itself) ----
    {
        const int mbase = 16 * wv + quad * 4;
#define SPLITW(ACC, NT, HIOFF, LOOFF) { \
        int n = 16 * NT + l15; \
        us4 hh, ll; \
        hh[0] = f2bf(ACC[0]); ll[0] = f2bf(ACC[0] - bf2f(hh[0])); \
        hh[1] = f2bf(ACC[1]); ll[1] = f2bf(ACC[1] - bf2f(hh[1])); \
        hh[2] = f2bf(ACC[2]); ll[2] = f2bf(ACC[2] - bf2f(hh[2])); \
        hh[3] = f2bf(ACC[3]); ll[3] = f2bf(ACC[3] - bf2f(hh[3])); \
        *(us4*)&SH[(HIOFF) + n * 72 + mbase] = hh; \
        *(us4*)&SH[(LOOFF) + n * 72 + mbase] = ll; }
        SPLITW(y0, 0, 26624, 31232) SPLITW(y1, 1, 26624, 31232)
        SPLITW(y2, 2, 26624, 31232) SPLITW(y3, 3, 26624, 31232)
        SPLITW(za0, 0, 17408, 22016) SPLITW(za1, 1, 17408, 22016)
        SPLITW(za2, 2, 17408, 22016) SPLITW(za3, 3, 17408, 22016)
#undef SPLITW
    }
    __syncthreads();      // (4) A2 + YT staged

    // ---- P2: Z = A2 @ Y, 3-term split ----
    f32x4 z0 = {0,0,0,0}, z1 = {0,0,0,0}, z2 = {0,0,0,0}, z3 = {0,0,0,0};
    {
        const int arow = 17408 + (16 * wv + l15) * 72 + quad * 8;
#pragma unroll
        for (int c = 0; c < 2; ++c) {
            bf16x8 ahi = *(bf16x8*)&SH[arow + c * 32];
            bf16x8 alo = *(bf16x8*)&SH[4608 + arow + c * 32];
#define P2TILE(ACC, NT) { \
            int bo = 26624 + (16 * NT + l15) * 72 + quad * 8 + c * 32; \
            bf16x8 bhi = *(bf16x8*)&SH[bo]; \
            bf16x8 blo = *(bf16x8*)&SH[4608 + bo]; \
            ACC = __builtin_amdgcn_mfma_f32_16x16x32_bf16(ahi, bhi, ACC, 0, 0, 0); \
            ACC = __builtin_amdgcn_mfma_f32_16x16x32_bf16(ahi, blo, ACC, 0, 0, 0); \
            ACC = __builtin_amdgcn_mfma_f32_16x16x32_bf16(alo, bhi, ACC, 0, 0, 0); }
            P2TILE(z0, 0) P2TILE(z1, 1) P2TILE(z2, 2) P2TILE(z3, 3)
#undef P2TILE
        }
    }

    // ---- epilogue: +b1, relu, mask pad rows, partial pool ----
    {
        const int mbase = 16 * wv + quad * 4;
        const int slot = 4 * wv + quad;
#define POOL(ACC, NT) { \
        int n = 16 * NT + l15; \
        float bn = b1S[n]; \
        float p = 0.f; \
        if (mbase + 0 < 62) p += fmaxf(ACC[0] + bn, 0.f); \
        if (mbase + 1 < 62) p += fmaxf(ACC[1] + bn, 0.f); \
        if (mbase + 2 < 62) p += fmaxf(ACC[2] + bn, 0.f); \
        if (mbase + 3 < 62) p += fmaxf(ACC[3] + bn, 0.f); \
        partial[n * 17 + slot] = p; }
        POOL(z0, 0) POOL(z1, 1) POOL(z2, 2) POOL(z3, 3)
#undef POOL
    }
    __syncthreads();      // (5) partials ready

    // ---- wave-0 tail: pool-reduce, latent write, logits via shuffle, log_softmax ----
    if (t < HD) {
        float s = 0.f;
#pragma unroll
        for (int q = 0; q < 16; ++q) s += partial[t * 17 + q];
        out[(size_t)g * HD + t] = s;
        float l0 = s * W2[t];                 // W2 rows: [c][h], 768 B, L2-hot
        float l1 = s * W2[64 + t];
        float l2 = s * W2[128 + t];
#pragma unroll
        for (int off = 32; off > 0; off >>= 1) {
            l0 += __shfl_down(l0, off);
            l1 += __shfl_down(l1, off);
            l2 += __shfl_down(l2, off);
        }
        if (t == 0) {
            l0 += b2[0]; l1 += b2[1]; l2 += b2[2];
            float m = fmaxf(l0, fmaxf(l1, l2));
            float lse = m + logf(expf(l0 - m) + expf(l1 - m) + expf(l2 - m));
            float* lp = out + (size_t)BGR * HD + (size_t)g * NC;
            lp[0] = l0 - lse; lp[1] = l1 - lse; lp[2] = l2 - lse;
        }
    }
}

extern "C" void kernel_launch(void* const* d_in, const int* in_sizes, int n_in,
                              void* d_out, int out_size, void* d_ws, size_t ws_size,
                              hipStream_t stream) {
    const float* x    = (const float*)d_in[0];
    const float* tril = (const float*)d_in[1];
    const float* W1   = (const float*)d_in[2];
    const float* b1   = (const float*)d_in[3];
    const float* W2   = (const float*)d_in[4];
    const float* b2   = (const float*)d_in[5];
    float* out = (float*)d_out;

    gcn_all<<<BGR, 256, 0, stream>>>(x, tril, W1, b1, W2, b2, out);
}

// Round 4
// 92.476 us; speedup vs baseline: 1.1369x; 1.0299x over previous
//
#include <hip/hip_runtime.h>
#include <math.h>

#define NN  62
#define BGR 512
#define FIN 128
#define HD  64
#define NC  3

typedef __attribute__((ext_vector_type(8))) short          bf16x8;
typedef __attribute__((ext_vector_type(4))) float          f32x4;
typedef __attribute__((ext_vector_type(4))) unsigned short us4;

static __device__ __forceinline__ unsigned short f2bf(float f) {
    union { float f; unsigned u; } v; v.f = f;
    unsigned u = v.u;
    return (unsigned short)((u + 0x7fffu + ((u >> 16) & 1u)) >> 16);   // RNE
}
static __device__ __forceinline__ float bf2f(unsigned short h) {
    union { unsigned u; float f; } v; v.u = ((unsigned)h) << 16;
    return v.f;
}

// v5: 2 graphs per block. 256 blocks x 512 threads (8 waves).
//   waves 0-3 <-> graph 2g   (gsel=0), waves 4-7 <-> graph 2g+1 (gsel=1).
// Graph-invariant work done ONCE per block (was once per graph):
//   - W1 split-staging: waves 4-7 only, concurrent with dinv on waves 0-3
//   - dinv + A-build: waves 0-3 (v4's all-thread scheme on 256 threads)
//   - A^2: 8-way split, each wave computes 2 of 8 (row-group x NT-pair) tiles;
//     per-tile MFMA chain order identical to v4 -> bit-identical output.
// Barriers: 5 per block = 2.5 per graph (was 5 per graph).
// LDS map (ushort offsets in SH):
//  WHI [0,8704) stride 136 | WLO [8704,17408)
//  AHI [17408,22016) stride 72 | ALO [22016,26624)   (overwritten by A2HI/LO)
//  YT_A HI [26624,31232) | LO [31232,35840)
//  YT_B HI [35840,40448) | LO [40448,45056)
// Total 90112 B + TAIL 9216 B ~= 99 KB -> 1 block/CU, 8 waves = 2/SIMD (same
// SIMD occupancy as v4's 2 blocks x 4 waves).
__global__ __launch_bounds__(512) void gcn_all(
    const float* __restrict__ x, const float* __restrict__ tril,
    const float* __restrict__ W1, const float* __restrict__ b1,
    const float* __restrict__ W2, const float* __restrict__ b2,
    float* __restrict__ out) {
    __shared__ unsigned short SH[45056];          // 88 KB
    __shared__ float TAIL[2176 + 64 + 64];        // partial[2](64x17), b1S(64), dinv(64)
    float* partial = TAIL;
    float* b1S     = TAIL + 2176;
    float* dinvS   = TAIL + 2240;

    const int t = threadIdx.x;
    const int gb = blockIdx.x;
    const int lane = t & 63, wv = t >> 6, quad = lane >> 4, l15 = lane & 15;
    const int w4 = wv & 3, gsel = wv >> 2;
    const int graph = 2 * gb + gsel;

    if (t < 16) *(float4*)&b1S[4 * t] = ((const float4*)b1)[t];

    // ---- X fragments (own graph): direct global -> regs. Rows 62,63 zeroed. ----
    bf16x8 xh[4], xl[4];
    {
        const int xr = 16 * w4 + l15;
        if (xr < NN) {
            const float* xrow = x + (size_t)graph * NN * FIN + (size_t)xr * FIN + quad * 8;
#pragma unroll
            for (int c = 0; c < 4; ++c) {
                float4 a = *(const float4*)(xrow + c * 32);
                float4 b = *(const float4*)(xrow + c * 32 + 4);
                float vv[8] = {a.x, a.y, a.z, a.w, b.x, b.y, b.z, b.w};
#pragma unroll
                for (int k = 0; k < 8; ++k) {
                    unsigned short h = f2bf(vv[k]);
                    xh[c][k] = (short)h;
                    xl[c][k] = (short)f2bf(vv[k] - bf2f(h));
                }
            }
        } else {
            bf16x8 zv = {0, 0, 0, 0, 0, 0, 0, 0};
#pragma unroll
            for (int c = 0; c < 4; ++c) { xh[c] = zv; xl[c] = zv; }
        }
    }

    const int arow_i = 16 * w4 + l15;      // this thread's A row (waves 0-3)
    const int jbase  = 16 * quad;          // this thread's A col-chunk
    float wreg[16];
    float dinv_r = 0.f;

    if (gsel == 1) {
        // ---- waves 4-7: stage W1 split (invariant; once per block) ----
        const float4* w14 = (const float4*)W1;
        for (int e = t - 256; e < 2048; e += 256) {
            int h = e >> 5, f4 = e & 31;
            float4 v = w14[e];
            us4 hh, ll;
            hh[0] = f2bf(v.x); ll[0] = f2bf(v.x - bf2f(hh[0]));
            hh[1] = f2bf(v.y); ll[1] = f2bf(v.y - bf2f(hh[1]));
            hh[2] = f2bf(v.z); ll[2] = f2bf(v.z - bf2f(hh[2]));
            hh[3] = f2bf(v.w); ll[3] = f2bf(v.w - bf2f(hh[3]));
            *(us4*)&SH[       h * 136 + f4 * 4] = hh;
            *(us4*)&SH[8704 + h * 136 + f4 * 4] = ll;
        }
    } else {
        // ---- waves 0-3: dinv, all-thread parallel; W_sym tile kept in regs ----
        float ps = 0.f;
#pragma unroll
        for (int jj = 0; jj < 16; ++jj) {
            int j = jbase + jj;
            float w = 0.f;
            if (arow_i < NN && j < NN) {
                int hi = arow_i > j ? arow_i : j;
                int lo = arow_i > j ? j : arow_i;
                w = tril[hi * (hi + 1) / 2 + lo];
            }
            wreg[jj] = w;
            ps += fabsf(w);
        }
        ps += __shfl_xor(ps, 16);          // quads 0<->1, 2<->3
        ps += __shfl_xor(ps, 32);          // quads {0,2}<->{1,3}
        dinv_r = (ps > 0.f) ? (1.0f / sqrtf(ps)) : 0.f;   // 0 for rows >=62
        if (lane < 16) dinvS[16 * w4 + lane] = dinv_r;
    }
    __syncthreads();      // (1) dinvS ready; W staged

    if (gsel == 0) {
        // ---- A = D^-1/2 W D^-1/2 split-bf16 from registers ----
        const float di = dinv_r;
#pragma unroll
        for (int k = 0; k < 4; ++k) {
            float4 d4 = *(float4*)&dinvS[jbase + 4 * k];
            float dja[4] = {d4.x, d4.y, d4.z, d4.w};
            us4 hh, ll;
#pragma unroll
            for (int e = 0; e < 4; ++e) {
                float v = di * wreg[4 * k + e] * dja[e];
                hh[e] = f2bf(v);
                ll[e] = f2bf(v - bf2f(hh[e]));
            }
            *(us4*)&SH[17408 + arow_i * 72 + jbase + 4 * k] = hh;
            *(us4*)&SH[22016 + arow_i * 72 + jbase + 4 * k] = ll;
        }
    }
    __syncthreads();      // (2) A staged

    // ---- A^2 = A @ A, 8-way split: wave computes NT tiles {2*gsel, 2*gsel+1}
    //      for rows 16*w4.. ; 3-term split (lo*lo dropped) ----
    f32x4 za0 = {0,0,0,0}, za1 = {0,0,0,0};
    {
        const int arow = 17408 + arow_i * 72 + quad * 8;
        const int nt0 = 2 * gsel;
#pragma unroll
        for (int c = 0; c < 2; ++c) {
            bf16x8 ahi = *(bf16x8*)&SH[arow + c * 32];
            bf16x8 alo = *(bf16x8*)&SH[4608 + arow + c * 32];
#define ATILE(ACC, NT) { \
            int bo = 17408 + (16 * (NT) + l15) * 72 + quad * 8 + c * 32; \
            bf16x8 bhi = *(bf16x8*)&SH[bo]; \
            bf16x8 blo = *(bf16x8*)&SH[4608 + bo]; \
            ACC = __builtin_amdgcn_mfma_f32_16x16x32_bf16(ahi, bhi, ACC, 0, 0, 0); \
            ACC = __builtin_amdgcn_mfma_f32_16x16x32_bf16(ahi, blo, ACC, 0, 0, 0); \
            ACC = __builtin_amdgcn_mfma_f32_16x16x32_bf16(alo, bhi, ACC, 0, 0, 0); }
            ATILE(za0, nt0) ATILE(za1, nt0 + 1)
#undef ATILE
        }
    }

    // ---- P1: Y = X @ W1^T (own graph; A-frags from regs), 3-term split ----
    f32x4 y0 = {0,0,0,0}, y1 = {0,0,0,0}, y2 = {0,0,0,0}, y3 = {0,0,0,0};
    {
#pragma unroll
        for (int c = 0; c < 4; ++c) {
            bf16x8 ahi = xh[c];
            bf16x8 alo = xl[c];
#define P1TILE(ACC, NT) { \
            int bo = (16 * (NT) + l15) * 136 + quad * 8 + c * 32; \
            bf16x8 bhi = *(bf16x8*)&SH[bo]; \
            bf16x8 blo = *(bf16x8*)&SH[8704 + bo]; \
            ACC = __builtin_amdgcn_mfma_f32_16x16x32_bf16(ahi, bhi, ACC, 0, 0, 0); \
            ACC = __builtin_amdgcn_mfma_f32_16x16x32_bf16(ahi, blo, ACC, 0, 0, 0); \
            ACC = __builtin_amdgcn_mfma_f32_16x16x32_bf16(alo, bhi, ACC, 0, 0, 0); }
            P1TILE(y0, 0) P1TILE(y1, 1) P1TILE(y2, 2) P1TILE(y3, 3)
#undef P1TILE
        }
    }
    __syncthreads();      // (3) all A/W-region reads done -> may overwrite A with A2

    // ---- write YT (own graph region) and A2 (symmetric -> transposed == itself) ----
    const int ytbase = 26624 + gsel * 9216;
    {
        const int mbase = 16 * w4 + quad * 4;
#define SPLITW(ACC, NT, HIOFF, LOOFF) { \
        int n = 16 * (NT) + l15; \
        us4 hh, ll; \
        hh[0] = f2bf(ACC[0]); ll[0] = f2bf(ACC[0] - bf2f(hh[0])); \
        hh[1] = f2bf(ACC[1]); ll[1] = f2bf(ACC[1] - bf2f(hh[1])); \
        hh[2] = f2bf(ACC[2]); ll[2] = f2bf(ACC[2] - bf2f(hh[2])); \
        hh[3] = f2bf(ACC[3]); ll[3] = f2bf(ACC[3] - bf2f(hh[3])); \
        *(us4*)&SH[(HIOFF) + n * 72 + mbase] = hh; \
        *(us4*)&SH[(LOOFF) + n * 72 + mbase] = ll; }
        SPLITW(y0, 0, ytbase, ytbase + 4608) SPLITW(y1, 1, ytbase, ytbase + 4608)
        SPLITW(y2, 2, ytbase, ytbase + 4608) SPLITW(y3, 3, ytbase, ytbase + 4608)
        SPLITW(za0, 2 * gsel,     17408, 22016)
        SPLITW(za1, 2 * gsel + 1, 17408, 22016)
#undef SPLITW
    }
    __syncthreads();      // (4) A2 + both YT staged

    // ---- P2: Z = A2 @ Y (own graph), 3-term split ----
    f32x4 z0 = {0,0,0,0}, z1 = {0,0,0,0}, z2 = {0,0,0,0}, z3 = {0,0,0,0};
    {
        const int arow = 17408 + arow_i * 72 + quad * 8;
#pragma unroll
        for (int c = 0; c < 2; ++c) {
            bf16x8 ahi = *(bf16x8*)&SH[arow + c * 32];
            bf16x8 alo = *(bf16x8*)&SH[4608 + arow + c * 32];
#define P2TILE(ACC, NT) { \
            int bo = ytbase + (16 * (NT) + l15) * 72 + quad * 8 + c * 32; \
            bf16x8 bhi = *(bf16x8*)&SH[bo]; \
            bf16x8 blo = *(bf16x8*)&SH[4608 + bo]; \
            ACC = __builtin_amdgcn_mfma_f32_16x16x32_bf16(ahi, bhi, ACC, 0, 0, 0); \
            ACC = __builtin_amdgcn_mfma_f32_16x16x32_bf16(ahi, blo, ACC, 0, 0, 0); \
            ACC = __builtin_amdgcn_mfma_f32_16x16x32_bf16(alo, bhi, ACC, 0, 0, 0); }
            P2TILE(z0, 0) P2TILE(z1, 1) P2TILE(z2, 2) P2TILE(z3, 3)
#undef P2TILE
        }
    }

    // ---- epilogue: +b1, relu, mask pad rows, partial pool (own graph) ----
    {
        const int mbase = 16 * w4 + quad * 4;
        const int slot = 4 * w4 + quad;
        float* part = partial + gsel * 1088;
#define POOL(ACC, NT) { \
        int n = 16 * (NT) + l15; \
        float bn = b1S[n]; \
        float p = 0.f; \
        if (mbase + 0 < 62) p += fmaxf(ACC[0] + bn, 0.f); \
        if (mbase + 1 < 62) p += fmaxf(ACC[1] + bn, 0.f); \
        if (mbase + 2 < 62) p += fmaxf(ACC[2] + bn, 0.f); \
        if (mbase + 3 < 62) p += fmaxf(ACC[3] + bn, 0.f); \
        part[n * 17 + slot] = p; }
        POOL(z0, 0) POOL(z1, 1) POOL(z2, 2) POOL(z3, 3)
#undef POOL
    }
    __syncthreads();      // (5) partials ready

    // ---- tails: wave 0 -> graph 2g, wave 4 -> graph 2g+1 ----
    int tg = -1, tt = 0;
    if (t < 64)                    { tg = 0; tt = t; }
    else if (t >= 256 && t < 320)  { tg = 1; tt = t - 256; }
    if (tg >= 0) {
        const float* part = partial + tg * 1088;
        const int gr = 2 * gb + tg;
        float s = 0.f;
#pragma unroll
        for (int q = 0; q < 16; ++q) s += part[tt * 17 + q];
        out[(size_t)gr * HD + tt] = s;
        float l0 = s * W2[tt];                // W2 rows: [c][h], 768 B, L2-hot
        float l1 = s * W2[64 + tt];
        float l2 = s * W2[128 + tt];
#pragma unroll
        for (int off = 32; off > 0; off >>= 1) {
            l0 += __shfl_down(l0, off);
            l1 += __shfl_down(l1, off);
            l2 += __shfl_down(l2, off);
        }
        if (tt == 0) {
            l0 += b2[0]; l1 += b2[1]; l2 += b2[2];
            float m = fmaxf(l0, fmaxf(l1, l2));
            float lse = m + logf(expf(l0 - m) + expf(l1 - m) + expf(l2 - m));
            float* lp = out + (size_t)BGR * HD + (size_t)gr * NC;
            lp[0] = l0 - lse; lp[1] = l1 - lse; lp[2] = l2 - lse;
        }
    }
}

extern "C" void kernel_launch(void* const* d_in, const int* in_sizes, int n_in,
                              void* d_out, int out_size, void* d_ws, size_t ws_size,
                              hipStream_t stream) {
    const float* x    = (const float*)d_in[0];
    const float* tril = (const float*)d_in[1];
    const float* W1   = (const float*)d_in[2];
    const float* b1   = (const float*)d_in[3];
    const float* W2   = (const float*)d_in[4];
    const float* b2   = (const float*)d_in[5];
    float* out = (float*)d_out;

    gcn_all<<<BGR / 2, 512, 0, stream>>>(x, tril, W1, b1, W2, b2, out);
}